// Round 3
// baseline (241.574 us; speedup 1.0000x reference)
//
#include <hip/hip_runtime.h>
#include <math.h>

#define BLK 256

struct Elem {
    float l1[3], l2[3], s1[3], s2[3], R1[9], R2[9];
};

__device__ __forceinline__ void load_elem(
    const float* __restrict__ loc1, const float* __restrict__ scale1,
    const float* __restrict__ rot1, const float* __restrict__ loc2,
    const float* __restrict__ scale2, const float* __restrict__ rot2,
    int idx, Elem& e)
{
    // 36 B -> global_load_dwordx4 + dwordx4 + dword (4 B align is legal);
    // 12 B -> global_load_dwordx3. All independent; no barrier anywhere.
    __builtin_memcpy(e.R1, rot1   + (size_t)idx * 9, 36);
    __builtin_memcpy(e.R2, rot2   + (size_t)idx * 9, 36);
    __builtin_memcpy(e.l1, loc1   + (size_t)idx * 3, 12);
    __builtin_memcpy(e.l2, loc2   + (size_t)idx * 3, 12);
    __builtin_memcpy(e.s1, scale1 + (size_t)idx * 3, 12);
    __builtin_memcpy(e.s2, scale2 + (size_t)idx * 3, 12);
}

__device__ __forceinline__ float compute(const Elem& e)
{
    const float dx = e.l1[0] - e.l2[0];
    const float dy = e.l1[1] - e.l2[1];
    const float dz = e.l1[2] - e.l2[2];
    const float ld2 = dx * dx + dy * dy + dz * dz;

    const float* R1 = e.R1;
    const float* R2 = e.R2;
    const float sa = e.s1[0], sb = e.s1[1], sc = e.s1[2];
    const float ua = e.s2[0], ub = e.s2[1], uc = e.s2[2];

    // M2 = R2 diag(s2) R2^T (symmetric, 6 entries)
    const float m00 = ua * R2[0] * R2[0] + ub * R2[1] * R2[1] + uc * R2[2] * R2[2];
    const float m01 = ua * R2[0] * R2[3] + ub * R2[1] * R2[4] + uc * R2[2] * R2[5];
    const float m02 = ua * R2[0] * R2[6] + ub * R2[1] * R2[7] + uc * R2[2] * R2[8];
    const float m11 = ua * R2[3] * R2[3] + ub * R2[4] * R2[4] + uc * R2[5] * R2[5];
    const float m12 = ua * R2[3] * R2[6] + ub * R2[4] * R2[7] + uc * R2[5] * R2[8];
    const float m22 = ua * R2[6] * R2[6] + ub * R2[7] * R2[7] + uc * R2[8] * R2[8];

    // A = M2 * R1
    const float A0 = m00 * R1[0] + m01 * R1[3] + m02 * R1[6];
    const float A1 = m00 * R1[1] + m01 * R1[4] + m02 * R1[7];
    const float A2 = m00 * R1[2] + m01 * R1[5] + m02 * R1[8];
    const float A3 = m01 * R1[0] + m11 * R1[3] + m12 * R1[6];
    const float A4 = m01 * R1[1] + m11 * R1[4] + m12 * R1[7];
    const float A5 = m01 * R1[2] + m11 * R1[5] + m12 * R1[8];
    const float A6 = m02 * R1[0] + m12 * R1[3] + m22 * R1[6];
    const float A7 = m02 * R1[1] + m12 * R1[4] + m22 * R1[7];
    const float A8 = m02 * R1[2] + m12 * R1[5] + m22 * R1[8];

    // T = R1^T * A — exactly symmetric (M2 symmetric), need 6 entries only
    const float t00 = R1[0] * A0 + R1[3] * A3 + R1[6] * A6;
    const float t01 = R1[0] * A1 + R1[3] * A4 + R1[6] * A7;
    const float t02 = R1[0] * A2 + R1[3] * A5 + R1[6] * A8;
    const float t11 = R1[1] * A1 + R1[4] * A4 + R1[7] * A7;
    const float t12 = R1[1] * A2 + R1[4] * A5 + R1[7] * A8;
    const float t22 = R1[2] * A2 + R1[5] * A5 + R1[8] * A8;

    // Eigenvalues of E = D T D equal eigenvalues of G = T diag(s1)
    // (similarity). Characteristic poly: l^3 - c2 l^2 + c1 l - c0.
    const float c2 = t00 * sa + t11 * sb + t22 * sc;
    const float g2 = t00 * t00 * sa * sa + t11 * t11 * sb * sb + t22 * t22 * sc * sc
                   + 2.0f * (t01 * t01 * sa * sb + t02 * t02 * sa * sc + t12 * t12 * sb * sc);
    const float c1 = 0.5f * (c2 * c2 - g2);
    const float detT = t00 * (t11 * t22 - t12 * t12)
                     - t01 * (t01 * t22 - t12 * t02)
                     + t02 * (t01 * t12 - t11 * t02);
    const float c0 = detT * sa * sb * sc;

    // Depressed cubic x^3 + p x + q, l = x + m
    const float m  = c2 * (1.0f / 3.0f);
    const float p  = c1 - c2 * m;                       // <= 0 for real eigs
    const float q  = c1 * m - 2.0f * m * m * m - c0;
    const float s  = __builtin_amdgcn_sqrtf(fmaxf(-p * (1.0f / 3.0f), 0.0f));
    const float s3 = 2.0f * s * s * s;
    const float inv = __builtin_amdgcn_rcpf(fmaxf(s3, 1e-30f));
    float u = -q * inv;
    u = fminf(fmaxf(u, -1.0f), 1.0f);

    // fast acos (Hastings), max err ~7e-5 rad
    const float au = fabsf(u);
    const float rr = __builtin_amdgcn_sqrtf(1.0f - au) *
        (1.5707288f + au * (-0.2121144f + au * (0.0742610f + au * (-0.0187293f))));
    const float ac = (u < 0.0f) ? (3.14159265358979f - rr) : rr;

    // v_cos_f32 takes revolutions: phi_rev = ac/(3*2pi)
    const float phi = ac * (1.0f / (3.0f * 6.283185307179586f));
    const float x0 = 2.0f * s * __builtin_amdgcn_cosf(phi);
    const float x1 = 2.0f * s * __builtin_amdgcn_cosf(phi - (1.0f / 3.0f));
    const float e0 = x0 + m;
    const float e1 = x1 + m;
    const float e2 = c2 - e0 - e1;

    const float tr = __builtin_amdgcn_sqrtf(fabsf(e0))
                   + __builtin_amdgcn_sqrtf(fabsf(e1))
                   + __builtin_amdgcn_sqrtf(fabsf(e2));

    float cw = (sa + sb + sc) + (ua + ub + uc) - 2.0f * tr;
    cw = fmaxf(cw, 0.0f);
    return __builtin_amdgcn_sqrtf(ld2 + cw);
}

__global__ __launch_bounds__(BLK, 4) void wasserstein_kernel(
    const float* __restrict__ loc1,   const float* __restrict__ scale1,
    const float* __restrict__ rot1,   const float* __restrict__ loc2,
    const float* __restrict__ scale2, const float* __restrict__ rot2,
    float* __restrict__ out, int S)
{
    // 4 elements per thread at stride S, depth-2 software pipeline:
    // loads for the next element stay in flight while computing the current.
    const int t = blockIdx.x * BLK + threadIdx.x;

    Elem a, b;
    load_elem(loc1, scale1, rot1, loc2, scale2, rot2, t, a);
    load_elem(loc1, scale1, rot1, loc2, scale2, rot2, t + S, b);

    const float r0 = compute(a);
    load_elem(loc1, scale1, rot1, loc2, scale2, rot2, t + 2 * S, a);
    out[t] = r0;

    const float r1 = compute(b);
    load_elem(loc1, scale1, rot1, loc2, scale2, rot2, t + 3 * S, b);
    out[t + S] = r1;

    out[t + 2 * S] = compute(a);
    out[t + 3 * S] = compute(b);
}

extern "C" void kernel_launch(void* const* d_in, const int* in_sizes, int n_in,
                              void* d_out, int out_size, void* d_ws, size_t ws_size,
                              hipStream_t stream) {
    const float* loc1   = (const float*)d_in[0];
    const float* scale1 = (const float*)d_in[1];
    const float* rot1   = (const float*)d_in[2];
    const float* loc2   = (const float*)d_in[3];
    const float* scale2 = (const float*)d_in[4];
    const float* rot2   = (const float*)d_in[5];
    float* out = (float*)d_out;

    const int B = in_sizes[0] / 3;   // 2097152; divisible by 4*BLK
    const int S = B / 4;             // elements per phase
    const int grid = S / BLK;        // 2048 blocks

    wasserstein_kernel<<<grid, BLK, 0, stream>>>(loc1, scale1, rot1,
                                                 loc2, scale2, rot2, out, S);
}